// Round 6
// baseline (1141.485 us; speedup 1.0000x reference)
//
#include <hip/hip_runtime.h>
#include <math.h>

#define VOCAB   50000
#define EMBED   256
#define HIDDEN  64
#define G4      256     // 4*HIDDEN
#define BATCH   64
#define TSEQ    2048
#define NUM_OUT 16

typedef _Float16 h2 __attribute__((ext_vector_type(2)));

__device__ __forceinline__ float fexp2f(float x) { return __builtin_amdgcn_exp2f(x); }
__device__ __forceinline__ float frcpf(float x)  { return __builtin_amdgcn_rcpf(x); }
__device__ __forceinline__ float fsigmoidf(float x) {
    return frcpf(1.0f + fexp2f(-1.44269504f * x));
}
// tanh(x) = 1 - 2/(2^(2x*log2e)+1); saturates correctly at +-inf
__device__ __forceinline__ float ftanhf(float x) {
    float e = fexp2f(2.88539008f * x);
    return 1.0f - 2.0f * frcpf(e + 1.0f);
}

// v_dot2_f32_f16 via inline asm with FORCED operand classes:
//   a (weight) -> "v": arch VGPR. Rounds 2-5 allocated only 96 arch VGPRs for
//     128 live weight values -> weights sat in AGPRs, costing ~128
//     v_accvgpr_read copies per step (~200 phantom VALU insts measured).
//     A "v" use-site makes AGPR residency cost a copy per use, so the
//     allocator keeps weights in arch VGPRs (budget fine at 1 wave/SIMD).
//   b (h broadcast) -> "s": readlane already produces an SGPR; VOP3P may read
//     one scalar src. Zero v_mov traffic.
__device__ __forceinline__ float dot2a(h2 a, int b, float c) {
    float r;
    asm("v_dot2_f32_f16 %0, %1, %2, %3"
        : "=v"(r)
        : "v"(__builtin_bit_cast(int, a)), "s"(b), "v"(c));
    return r;
}

// xor-1 neighbor exchange as pure-VALU DPP (quad_perm [1,0,3,2] = 0xB1)
__device__ __forceinline__ int dpp_xor1(int v) {
    return __builtin_amdgcn_update_dpp(0, v, 0xB1, 0xF, 0xF, true);
}
__device__ __forceinline__ int rl(int v, int lane) {
    return __builtin_amdgcn_readlane(v, lane);
}

#define REP32(M) M(0) M(1) M(2) M(3) M(4) M(5) M(6) M(7) \
                 M(8) M(9) M(10) M(11) M(12) M(13) M(14) M(15) \
                 M(16) M(17) M(18) M(19) M(20) M(21) M(22) M(23) \
                 M(24) M(25) M(26) M(27) M(28) M(29) M(30) M(31)

// ---------------------------------------------------------------------------
// proj[v][u][q] = dot(emb[v], W_ih[q*64+u]) + b_ih[q*64+u] + b_hh[q*64+u]
// Each thread owns the 4 gates of ONE unit -> coalesced float4 stores.
// ---------------------------------------------------------------------------
__global__ __launch_bounds__(256) void proj_kernel(
    const float* __restrict__ emb, const float* __restrict__ W_ih,
    const float* __restrict__ b_ih, const float* __restrict__ b_hh,
    float* __restrict__ proj)
{
    __shared__ __align__(16) float As[64][68]; // As[k][r] = emb[R0+r][kc*64+k]
    __shared__ __align__(16) float Bs[64][68]; // Bs[k][r] = W_ih[map(r)][kc*64+k]

    const int tid = threadIdx.x;
    const int R0 = blockIdx.x * 64;
    const int U0 = blockIdx.y * 16;   // 16 units per y-block (gridDim.y = 4)

    const int rr = (tid & 15) * 4;    // 4 emb rows
    const int gg = (tid >> 4) * 4;    // 4 tile-cols = gates 0..3 of unit U0+uu
    const int uu = tid >> 4;          // unit within the 16-unit group

    float acc[4][4] = {};

    for (int kc = 0; kc < 4; ++kc) {
        #pragma unroll
        for (int it = 0; it < 4; ++it) {
            int flat = (it * 256 + tid) * 4;
            int r = flat >> 6;
            int k = flat & 63;
            int row = R0 + r;
            float4 v = make_float4(0.f, 0.f, 0.f, 0.f);
            if (row < VOCAB)
                v = *(const float4*)&emb[(size_t)row * EMBED + kc * 64 + k];
            As[k + 0][r] = v.x; As[k + 1][r] = v.y;
            As[k + 2][r] = v.z; As[k + 3][r] = v.w;
            int wrow = (r & 3) * 64 + U0 + (r >> 2);   // gate (r&3), unit U0+(r>>2)
            float4 wv = *(const float4*)&W_ih[(size_t)wrow * EMBED + kc * 64 + k];
            Bs[k + 0][r] = wv.x; Bs[k + 1][r] = wv.y;
            Bs[k + 2][r] = wv.z; Bs[k + 3][r] = wv.w;
        }
        __syncthreads();

        #pragma unroll 8
        for (int k = 0; k < 64; ++k) {
            float4 a = *(const float4*)&As[k][rr];
            float4 b = *(const float4*)&Bs[k][gg];
            acc[0][0] = fmaf(a.x, b.x, acc[0][0]);
            acc[0][1] = fmaf(a.x, b.y, acc[0][1]);
            acc[0][2] = fmaf(a.x, b.z, acc[0][2]);
            acc[0][3] = fmaf(a.x, b.w, acc[0][3]);
            acc[1][0] = fmaf(a.y, b.x, acc[1][0]);
            acc[1][1] = fmaf(a.y, b.y, acc[1][1]);
            acc[1][2] = fmaf(a.y, b.z, acc[1][2]);
            acc[1][3] = fmaf(a.y, b.w, acc[1][3]);
            acc[2][0] = fmaf(a.z, b.x, acc[2][0]);
            acc[2][1] = fmaf(a.z, b.y, acc[2][1]);
            acc[2][2] = fmaf(a.z, b.z, acc[2][2]);
            acc[2][3] = fmaf(a.z, b.w, acc[2][3]);
            acc[3][0] = fmaf(a.w, b.x, acc[3][0]);
            acc[3][1] = fmaf(a.w, b.y, acc[3][1]);
            acc[3][2] = fmaf(a.w, b.z, acc[3][2]);
            acc[3][3] = fmaf(a.w, b.w, acc[3][3]);
        }
        __syncthreads();
    }

    float bias[4];
    #pragma unroll
    for (int q = 0; q < 4; ++q)
        bias[q] = b_ih[q * 64 + U0 + uu] + b_hh[q * 64 + U0 + uu];

    #pragma unroll
    for (int u = 0; u < 4; ++u) {
        int row = R0 + rr + u;
        if (row < VOCAB) {
            float4 o;
            o.x = acc[u][0] + bias[0];
            o.y = acc[u][1] + bias[1];
            o.z = acc[u][2] + bias[2];
            o.w = acc[u][3] + bias[3];
            *(float4*)&proj[(size_t)row * G4 + (U0 + uu) * 4] = o;  // coalesced
        }
    }
}

// ---------------------------------------------------------------------------
// Barrier-free LSTM scan: ONE wave per batch element, 64 CUs. Weights as 128
// named h2 values consumed ONLY by asm dot2 with "v" constraints (forces arch
// VGPR residency). h broadcast: batch all 32 readlanes first (SGPR results),
// then 128 dot2s read them as scalar srcs. Zero LDS/barriers in the loop.
// ---------------------------------------------------------------------------
__global__ __launch_bounds__(64, 1) void lstm_scan(
    const int* __restrict__ x, const float* __restrict__ proj,
    const float* __restrict__ W_hh,
    const float* __restrict__ bn_gamma, const float* __restrict__ bn_beta,
    const float* __restrict__ bn_mean, const float* __restrict__ bn_var,
    const float* __restrict__ fc_w, const float* __restrict__ fc_b,
    float* __restrict__ out)
{
    const int b = blockIdx.x;
    const int j = threadIdx.x;   // 0..63, hidden unit index

    __shared__ int   toks[TSEQ];
    __shared__ float hb_s[HIDDEN];

    for (int i = j; i < TSEQ; i += 64) toks[i] = x[b * TSEQ + i];
    __syncthreads();

    const float* Wi = &W_hh[(size_t)(0 * HIDDEN + j) * HIDDEN];
    const float* Wf = &W_hh[(size_t)(1 * HIDDEN + j) * HIDDEN];
    const float* Wg = &W_hh[(size_t)(2 * HIDDEN + j) * HIDDEN];
    const float* Wo = &W_hh[(size_t)(3 * HIDDEN + j) * HIDDEN];

    // 128 named h2 registers: wi0..wi31, wf0..wf31, wg0..wg31, wo0..wo31
#define W_DECL(n) h2 wi##n, wf##n, wg##n, wo##n;
    REP32(W_DECL)
#undef W_DECL

#define W_LOAD(n) { \
        float2 vi = *(const float2*)&Wi[2 * (n)]; \
        float2 vf = *(const float2*)&Wf[2 * (n)]; \
        float2 vg = *(const float2*)&Wg[2 * (n)]; \
        float2 vo = *(const float2*)&Wo[2 * (n)]; \
        wi##n = h2{(_Float16)vi.x, (_Float16)vi.y}; \
        wf##n = h2{(_Float16)vf.x, (_Float16)vf.y}; \
        wg##n = h2{(_Float16)vg.x, (_Float16)vg.y}; \
        wo##n = h2{(_Float16)vo.x, (_Float16)vo.y}; }
    REP32(W_LOAD)
#undef W_LOAD

    float h = 0.0f, c = 0.0f;
    int pk = 0;  // f16x2 (h_{2m}, h_{2m+1}) in even lane 2m; h=0 -> 0

    auto step = [&](const float4& gx) {
        float ai = gx.x, af = gx.y, ag = gx.z, ao = gx.w;  // gate order i,f,g,o
        float bi = 0.f, bf = 0.f, bg = 0.f, bo = 0.f;

        // phase 1: all 32 broadcasts (SGPR dests; hazards overlap each other)
#define H_COLLECT(n) int hh##n = rl(pk, 2 * (n));
        REP32(H_COLLECT)
#undef H_COLLECT

        // phase 2: 128 dot2s, 8 accumulation chains, weights pinned to "v"
#define W_DOT(n) \
        if ((n) & 1) { \
            bi = dot2a(wi##n, hh##n, bi); bf = dot2a(wf##n, hh##n, bf); \
            bg = dot2a(wg##n, hh##n, bg); bo = dot2a(wo##n, hh##n, bo); \
        } else { \
            ai = dot2a(wi##n, hh##n, ai); af = dot2a(wf##n, hh##n, af); \
            ag = dot2a(wg##n, hh##n, ag); ao = dot2a(wo##n, hh##n, ao); \
        }
        REP32(W_DOT)
#undef W_DOT

        ai += bi; af += bf; ag += bg; ao += bo;
        float i_ = fsigmoidf(ai);
        float f_ = fsigmoidf(af);
        float g_ = ftanhf(ag);
        float o_ = fsigmoidf(ao);
        c = fmaf(f_, c, i_ * g_);
        h = o_ * ftanhf(c);
        int hp = dpp_xor1(__float_as_int(h));
        pk = __builtin_bit_cast(int, __builtin_amdgcn_cvt_pkrtz(h, __int_as_float(hp)));
    };

    // 2-step-deep gx prefetch, tokens one unroll-iter ahead
    float4 g0 = *(const float4*)&proj[(size_t)toks[0] * G4 + j * 4];
    float4 g1 = *(const float4*)&proj[(size_t)toks[1] * G4 + j * 4];
    int tk0 = toks[2], tk1 = toks[3];

    for (int t = 0; t < TSEQ; t += 2) {
        int i4 = (t + 4 < TSEQ) ? t + 4 : TSEQ - 1;
        int i5 = (t + 5 < TSEQ) ? t + 5 : TSEQ - 1;
        int nk0 = toks[i4];
        int nk1 = toks[i5];
        float4 n0 = *(const float4*)&proj[(size_t)tk0 * G4 + j * 4];
        step(g0);
        float4 n1 = *(const float4*)&proj[(size_t)tk1 * G4 + j * 4];
        step(g1);
        g0 = n0; g1 = n1; tk0 = nk0; tk1 = nk1;
    }

    // epilogue: BatchNorm (running stats) then FC
    float hb = (h - bn_mean[j]) * rsqrtf(bn_var[j] + 1e-5f) * bn_gamma[j]
               + bn_beta[j];
    hb_s[j] = hb;
    __syncthreads();
    if (j < NUM_OUT) {
        float s0 = fc_b[j], s1 = 0.f, s2 = 0.f, s3 = 0.f;
        #pragma unroll
        for (int k = 0; k < HIDDEN; k += 4) {
            s0 = fmaf(hb_s[k + 0], fc_w[j * HIDDEN + k + 0], s0);
            s1 = fmaf(hb_s[k + 1], fc_w[j * HIDDEN + k + 1], s1);
            s2 = fmaf(hb_s[k + 2], fc_w[j * HIDDEN + k + 2], s2);
            s3 = fmaf(hb_s[k + 3], fc_w[j * HIDDEN + k + 3], s3);
        }
        out[b * NUM_OUT + j] = (s0 + s1) + (s2 + s3);
    }
}

// ---------------------------------------------------------------------------
extern "C" void kernel_launch(void* const* d_in, const int* in_sizes, int n_in,
                              void* d_out, int out_size, void* d_ws, size_t ws_size,
                              hipStream_t stream) {
    const int*   x        = (const int*)d_in[0];
    // d_in[1] = seq_lengths: unused by the reference computation
    const float* emb      = (const float*)d_in[2];
    const float* W_ih     = (const float*)d_in[3];
    const float* W_hh     = (const float*)d_in[4];
    const float* b_ih     = (const float*)d_in[5];
    const float* b_hh     = (const float*)d_in[6];
    const float* bn_gamma = (const float*)d_in[7];
    const float* bn_beta  = (const float*)d_in[8];
    const float* bn_mean  = (const float*)d_in[9];
    const float* bn_var   = (const float*)d_in[10];
    const float* fc_w     = (const float*)d_in[11];
    const float* fc_b     = (const float*)d_in[12];

    float* proj = (float*)d_ws;  // VOCAB * 256 * 4 B = 51.2 MB

    dim3 pgrid((VOCAB + 63) / 64, G4 / 64);
    proj_kernel<<<pgrid, 256, 0, stream>>>(emb, W_ih, b_ih, b_hh, proj);

    lstm_scan<<<BATCH, 64, 0, stream>>>(x, proj, W_hh,
                                        bn_gamma, bn_beta, bn_mean, bn_var,
                                        fc_w, fc_b, (float*)d_out);
}

// Round 7
// 1008.821 us; speedup vs baseline: 1.1315x; 1.1315x over previous
//
#include <hip/hip_runtime.h>
#include <math.h>

#define VOCAB   50000
#define EMBED   256
#define HIDDEN  64
#define G4      256     // 4*HIDDEN
#define BATCH   64
#define TSEQ    2048
#define NUM_OUT 16

typedef _Float16 h2 __attribute__((ext_vector_type(2)));

__device__ __forceinline__ float fexp2f(float x) { return __builtin_amdgcn_exp2f(x); }
__device__ __forceinline__ float frcpf(float x)  { return __builtin_amdgcn_rcpf(x); }
__device__ __forceinline__ float fsigmoidf(float x) {
    return frcpf(1.0f + fexp2f(-1.44269504f * x));
}
// tanh(x) = 1 - 2/(2^(2x*log2e)+1); saturates correctly at +-inf
__device__ __forceinline__ float ftanhf(float x) {
    float e = fexp2f(2.88539008f * x);
    return 1.0f - 2.0f * frcpf(e + 1.0f);
}

// f16x2 dot with fp32 accumulate — v_dot2_f32_f16 (builtin: let the compiler
// pick operand classes; round 6 proved forcing "v"/"s" via asm only adds
// copies and hazards)
__device__ __forceinline__ float dot2(h2 a, h2 b, float c) {
#if __has_builtin(__builtin_amdgcn_fdot2)
    return __builtin_amdgcn_fdot2(a, b, c, false);
#else
    float r;
    asm("v_dot2_f32_f16 %0, %1, %2, %3"
        : "=v"(r)
        : "v"(__builtin_bit_cast(int, a)), "v"(__builtin_bit_cast(int, b)), "v"(c));
    return r;
#endif
}

// xor-1 neighbor exchange as pure-VALU DPP (quad_perm [1,0,3,2] = 0xB1)
__device__ __forceinline__ int dpp_xor1(int v) {
    return __builtin_amdgcn_update_dpp(0, v, 0xB1, 0xF, 0xF, true);
}
__device__ __forceinline__ int rl(int v, int lane) {
    return __builtin_amdgcn_readlane(v, lane);
}

#define REP32(M) M(0) M(1) M(2) M(3) M(4) M(5) M(6) M(7) \
                 M(8) M(9) M(10) M(11) M(12) M(13) M(14) M(15) \
                 M(16) M(17) M(18) M(19) M(20) M(21) M(22) M(23) \
                 M(24) M(25) M(26) M(27) M(28) M(29) M(30) M(31)

// ---------------------------------------------------------------------------
// proj[v][u][q] = dot(emb[v], W_ih[q*64+u]) + b_ih[q*64+u] + b_hh[q*64+u]
// Each thread owns the 4 gates of ONE unit -> coalesced float4 stores.
// ---------------------------------------------------------------------------
__global__ __launch_bounds__(256) void proj_kernel(
    const float* __restrict__ emb, const float* __restrict__ W_ih,
    const float* __restrict__ b_ih, const float* __restrict__ b_hh,
    float* __restrict__ proj)
{
    __shared__ __align__(16) float As[64][68]; // As[k][r] = emb[R0+r][kc*64+k]
    __shared__ __align__(16) float Bs[64][68]; // Bs[k][r] = W_ih[map(r)][kc*64+k]

    const int tid = threadIdx.x;
    const int R0 = blockIdx.x * 64;
    const int U0 = blockIdx.y * 16;   // 16 units per y-block (gridDim.y = 4)

    const int rr = (tid & 15) * 4;    // 4 emb rows
    const int gg = (tid >> 4) * 4;    // 4 tile-cols = gates 0..3 of unit U0+uu
    const int uu = tid >> 4;          // unit within the 16-unit group

    float acc[4][4] = {};

    for (int kc = 0; kc < 4; ++kc) {
        #pragma unroll
        for (int it = 0; it < 4; ++it) {
            int flat = (it * 256 + tid) * 4;
            int r = flat >> 6;
            int k = flat & 63;
            int row = R0 + r;
            float4 v = make_float4(0.f, 0.f, 0.f, 0.f);
            if (row < VOCAB)
                v = *(const float4*)&emb[(size_t)row * EMBED + kc * 64 + k];
            As[k + 0][r] = v.x; As[k + 1][r] = v.y;
            As[k + 2][r] = v.z; As[k + 3][r] = v.w;
            int wrow = (r & 3) * 64 + U0 + (r >> 2);   // gate (r&3), unit U0+(r>>2)
            float4 wv = *(const float4*)&W_ih[(size_t)wrow * EMBED + kc * 64 + k];
            Bs[k + 0][r] = wv.x; Bs[k + 1][r] = wv.y;
            Bs[k + 2][r] = wv.z; Bs[k + 3][r] = wv.w;
        }
        __syncthreads();

        #pragma unroll 8
        for (int k = 0; k < 64; ++k) {
            float4 a = *(const float4*)&As[k][rr];
            float4 b = *(const float4*)&Bs[k][gg];
            acc[0][0] = fmaf(a.x, b.x, acc[0][0]);
            acc[0][1] = fmaf(a.x, b.y, acc[0][1]);
            acc[0][2] = fmaf(a.x, b.z, acc[0][2]);
            acc[0][3] = fmaf(a.x, b.w, acc[0][3]);
            acc[1][0] = fmaf(a.y, b.x, acc[1][0]);
            acc[1][1] = fmaf(a.y, b.y, acc[1][1]);
            acc[1][2] = fmaf(a.y, b.z, acc[1][2]);
            acc[1][3] = fmaf(a.y, b.w, acc[1][3]);
            acc[2][0] = fmaf(a.z, b.x, acc[2][0]);
            acc[2][1] = fmaf(a.z, b.y, acc[2][1]);
            acc[2][2] = fmaf(a.z, b.z, acc[2][2]);
            acc[2][3] = fmaf(a.z, b.w, acc[2][3]);
            acc[3][0] = fmaf(a.w, b.x, acc[3][0]);
            acc[3][1] = fmaf(a.w, b.y, acc[3][1]);
            acc[3][2] = fmaf(a.w, b.z, acc[3][2]);
            acc[3][3] = fmaf(a.w, b.w, acc[3][3]);
        }
        __syncthreads();
    }

    float bias[4];
    #pragma unroll
    for (int q = 0; q < 4; ++q)
        bias[q] = b_ih[q * 64 + U0 + uu] + b_hh[q * 64 + U0 + uu];

    #pragma unroll
    for (int u = 0; u < 4; ++u) {
        int row = R0 + rr + u;
        if (row < VOCAB) {
            float4 o;
            o.x = acc[u][0] + bias[0];
            o.y = acc[u][1] + bias[1];
            o.z = acc[u][2] + bias[2];
            o.w = acc[u][3] + bias[3];
            *(float4*)&proj[(size_t)row * G4 + (U0 + uu) * 4] = o;  // coalesced
        }
    }
}

// ---------------------------------------------------------------------------
// Barrier-free LSTM scan: ONE wave per batch element, 64 CUs.
// amdgpu_waves_per_eu(1,1): tell the allocator the target occupancy IS 1
// wave/EU, so it may spend up to the full 512-VGPR budget and keep the 128
// weight pairs in arch VGPRs (rounds 2-6: heuristic capped arch at 96 and
// parked weights in AGPRs/remat -> ~200 phantom VALU insts/step).
// All 32 h-broadcasts batched before the dot block (hazards overlap).
// ---------------------------------------------------------------------------
__global__ __attribute__((amdgpu_waves_per_eu(1, 1)))
__launch_bounds__(64) void lstm_scan(
    const int* __restrict__ x, const float* __restrict__ proj,
    const float* __restrict__ W_hh,
    const float* __restrict__ bn_gamma, const float* __restrict__ bn_beta,
    const float* __restrict__ bn_mean, const float* __restrict__ bn_var,
    const float* __restrict__ fc_w, const float* __restrict__ fc_b,
    float* __restrict__ out)
{
    const int b = blockIdx.x;
    const int j = threadIdx.x;   // 0..63, hidden unit index

    __shared__ int   toks[TSEQ];
    __shared__ float hb_s[HIDDEN];

    for (int i = j; i < TSEQ; i += 64) toks[i] = x[b * TSEQ + i];
    __syncthreads();

    const float* Wi = &W_hh[(size_t)(0 * HIDDEN + j) * HIDDEN];
    const float* Wf = &W_hh[(size_t)(1 * HIDDEN + j) * HIDDEN];
    const float* Wg = &W_hh[(size_t)(2 * HIDDEN + j) * HIDDEN];
    const float* Wo = &W_hh[(size_t)(3 * HIDDEN + j) * HIDDEN];

    // 128 named h2 registers: wi0..wi31, wf0..wf31, wg0..wg31, wo0..wo31
#define W_DECL(n) h2 wi##n, wf##n, wg##n, wo##n;
    REP32(W_DECL)
#undef W_DECL

#define W_LOAD(n) { \
        float2 vi = *(const float2*)&Wi[2 * (n)]; \
        float2 vf = *(const float2*)&Wf[2 * (n)]; \
        float2 vg = *(const float2*)&Wg[2 * (n)]; \
        float2 vo = *(const float2*)&Wo[2 * (n)]; \
        wi##n = h2{(_Float16)vi.x, (_Float16)vi.y}; \
        wf##n = h2{(_Float16)vf.x, (_Float16)vf.y}; \
        wg##n = h2{(_Float16)vg.x, (_Float16)vg.y}; \
        wo##n = h2{(_Float16)vo.x, (_Float16)vo.y}; }
    REP32(W_LOAD)
#undef W_LOAD

    float h = 0.0f, c = 0.0f;
    int pk = 0;  // f16x2 (h_{2m}, h_{2m+1}) in even lane 2m; h=0 -> 0

    auto step = [&](const float4& gx) {
        float ai = gx.x, af = gx.y, ag = gx.z, ao = gx.w;  // gate order i,f,g,o
        float bi = 0.f, bf = 0.f, bg = 0.f, bo = 0.f;

        // phase 1: all 32 broadcasts batched (readlane hazards overlap here)
#define H_COLLECT(n) int hh##n = rl(pk, 2 * (n));
        REP32(H_COLLECT)
#undef H_COLLECT

        // phase 2: 128 dot2s, 8 accumulation chains
#define W_DOT(n) { \
            h2 hv = __builtin_bit_cast(h2, hh##n); \
            if ((n) & 1) { \
                bi = dot2(wi##n, hv, bi); bf = dot2(wf##n, hv, bf); \
                bg = dot2(wg##n, hv, bg); bo = dot2(wo##n, hv, bo); \
            } else { \
                ai = dot2(wi##n, hv, ai); af = dot2(wf##n, hv, af); \
                ag = dot2(wg##n, hv, ag); ao = dot2(wo##n, hv, ao); \
            } }
        REP32(W_DOT)
#undef W_DOT

        ai += bi; af += bf; ag += bg; ao += bo;
        float i_ = fsigmoidf(ai);
        float f_ = fsigmoidf(af);
        float g_ = ftanhf(ag);
        float o_ = fsigmoidf(ao);
        c = fmaf(f_, c, i_ * g_);
        h = o_ * ftanhf(c);
        int hp = dpp_xor1(__float_as_int(h));
        pk = __builtin_bit_cast(int, __builtin_amdgcn_cvt_pkrtz(h, __int_as_float(hp)));
    };

    // 2-step-deep gx prefetch, tokens one unroll-iter ahead
    float4 g0 = *(const float4*)&proj[(size_t)toks[0] * G4 + j * 4];
    float4 g1 = *(const float4*)&proj[(size_t)toks[1] * G4 + j * 4];
    int tk0 = toks[2], tk1 = toks[3];

    for (int t = 0; t < TSEQ; t += 2) {
        int i4 = (t + 4 < TSEQ) ? t + 4 : TSEQ - 1;
        int i5 = (t + 5 < TSEQ) ? t + 5 : TSEQ - 1;
        int nk0 = toks[i4];
        int nk1 = toks[i5];
        float4 n0 = *(const float4*)&proj[(size_t)tk0 * G4 + j * 4];
        step(g0);
        float4 n1 = *(const float4*)&proj[(size_t)tk1 * G4 + j * 4];
        step(g1);
        g0 = n0; g1 = n1; tk0 = nk0; tk1 = nk1;
    }

    // epilogue: BatchNorm (running stats) then FC
    float hb = (h - bn_mean[j]) * rsqrtf(bn_var[j] + 1e-5f) * bn_gamma[j]
               + bn_beta[j];
    hb_s[j] = hb;
    __syncthreads();
    if (j < NUM_OUT) {
        float s0 = fc_b[j], s1 = 0.f, s2 = 0.f, s3 = 0.f;
        #pragma unroll
        for (int k = 0; k < HIDDEN; k += 4) {
            s0 = fmaf(hb_s[k + 0], fc_w[j * HIDDEN + k + 0], s0);
            s1 = fmaf(hb_s[k + 1], fc_w[j * HIDDEN + k + 1], s1);
            s2 = fmaf(hb_s[k + 2], fc_w[j * HIDDEN + k + 2], s2);
            s3 = fmaf(hb_s[k + 3], fc_w[j * HIDDEN + k + 3], s3);
        }
        out[b * NUM_OUT + j] = (s0 + s1) + (s2 + s3);
    }
}

// ---------------------------------------------------------------------------
extern "C" void kernel_launch(void* const* d_in, const int* in_sizes, int n_in,
                              void* d_out, int out_size, void* d_ws, size_t ws_size,
                              hipStream_t stream) {
    const int*   x        = (const int*)d_in[0];
    // d_in[1] = seq_lengths: unused by the reference computation
    const float* emb      = (const float*)d_in[2];
    const float* W_ih     = (const float*)d_in[3];
    const float* W_hh     = (const float*)d_in[4];
    const float* b_ih     = (const float*)d_in[5];
    const float* b_hh     = (const float*)d_in[6];
    const float* bn_gamma = (const float*)d_in[7];
    const float* bn_beta  = (const float*)d_in[8];
    const float* bn_mean  = (const float*)d_in[9];
    const float* bn_var   = (const float*)d_in[10];
    const float* fc_w     = (const float*)d_in[11];
    const float* fc_b     = (const float*)d_in[12];

    float* proj = (float*)d_ws;  // VOCAB * 256 * 4 B = 51.2 MB

    dim3 pgrid((VOCAB + 63) / 64, G4 / 64);
    proj_kernel<<<pgrid, 256, 0, stream>>>(emb, W_ih, b_ih, b_hh, proj);

    lstm_scan<<<BATCH, 64, 0, stream>>>(x, proj, W_hh,
                                        bn_gamma, bn_beta, bn_mean, bn_var,
                                        fc_w, fc_b, (float*)d_out);
}

// Round 8
// 956.024 us; speedup vs baseline: 1.1940x; 1.0552x over previous
//
#include <hip/hip_runtime.h>
#include <math.h>

#define VOCAB   50000
#define EMBED   256
#define HIDDEN  64
#define G4      256     // 4*HIDDEN
#define BATCH   64
#define TSEQ    2048
#define NUM_OUT 16

typedef _Float16 h2 __attribute__((ext_vector_type(2)));

__device__ __forceinline__ float fexp2f(float x) { return __builtin_amdgcn_exp2f(x); }
__device__ __forceinline__ float frcpf(float x)  { return __builtin_amdgcn_rcpf(x); }
__device__ __forceinline__ float fsigmoidf(float x) {
    return frcpf(1.0f + fexp2f(-1.44269504f * x));
}
// tanh(x) = 1 - 2/(2^(2x*log2e)+1); saturates correctly at +-inf
__device__ __forceinline__ float ftanhf(float x) {
    float e = fexp2f(2.88539008f * x);
    return 1.0f - 2.0f * frcpf(e + 1.0f);
}

// f16x2 dot with fp32 accumulate — v_dot2_f32_f16
__device__ __forceinline__ float dot2(h2 a, h2 b, float c) {
#if __has_builtin(__builtin_amdgcn_fdot2)
    return __builtin_amdgcn_fdot2(a, b, c, false);
#else
    float r;
    asm("v_dot2_f32_f16 %0, %1, %2, %3"
        : "=v"(r)
        : "v"(__builtin_bit_cast(int, a)), "v"(__builtin_bit_cast(int, b)), "v"(c));
    return r;
#endif
}

// xor-1 neighbor exchange as pure-VALU DPP (quad_perm [1,0,3,2] = 0xB1)
__device__ __forceinline__ int dpp_xor1(int v) {
    return __builtin_amdgcn_update_dpp(0, v, 0xB1, 0xF, 0xF, true);
}
__device__ __forceinline__ int rl(int v, int lane) {
    return __builtin_amdgcn_readlane(v, lane);
}

#define REP32(M) M(0) M(1) M(2) M(3) M(4) M(5) M(6) M(7) \
                 M(8) M(9) M(10) M(11) M(12) M(13) M(14) M(15) \
                 M(16) M(17) M(18) M(19) M(20) M(21) M(22) M(23) \
                 M(24) M(25) M(26) M(27) M(28) M(29) M(30) M(31)

// ---------------------------------------------------------------------------
// proj[v][g] = dot(emb[v], W_ih[g]) + b_ih[g] + b_hh[g]   (gate-major g)
// Round-1 layout: scan wave q lane j reads proj[v*256 + q*64 + j] -- lane-
// consecutive floats, perfectly coalesced. Stores here are coalesced float4.
// ---------------------------------------------------------------------------
__global__ __launch_bounds__(256) void proj_kernel(
    const float* __restrict__ emb, const float* __restrict__ W_ih,
    const float* __restrict__ b_ih, const float* __restrict__ b_hh,
    float* __restrict__ proj)
{
    __shared__ __align__(16) float As[64][68]; // As[k][r] = emb[R0+r][kc*64+k]
    __shared__ __align__(16) float Bs[64][68]; // Bs[k][g] = W_ih[G0+g][kc*64+k]

    const int tid = threadIdx.x;
    const int R0 = blockIdx.x * 64;
    const int G0 = blockIdx.y * 64;

    const int rr = (tid & 15) * 4;
    const int gg = (tid >> 4) * 4;

    float acc[4][4] = {};

    for (int kc = 0; kc < 4; ++kc) {
        #pragma unroll
        for (int it = 0; it < 4; ++it) {
            int flat = (it * 256 + tid) * 4;
            int r = flat >> 6;
            int k = flat & 63;
            int row = R0 + r;
            float4 v = make_float4(0.f, 0.f, 0.f, 0.f);
            if (row < VOCAB)
                v = *(const float4*)&emb[(size_t)row * EMBED + kc * 64 + k];
            As[k + 0][r] = v.x; As[k + 1][r] = v.y;
            As[k + 2][r] = v.z; As[k + 3][r] = v.w;
            float4 wv = *(const float4*)&W_ih[(size_t)(G0 + r) * EMBED + kc * 64 + k];
            Bs[k + 0][r] = wv.x; Bs[k + 1][r] = wv.y;
            Bs[k + 2][r] = wv.z; Bs[k + 3][r] = wv.w;
        }
        __syncthreads();

        #pragma unroll 8
        for (int k = 0; k < 64; ++k) {
            float4 a = *(const float4*)&As[k][rr];
            float4 b = *(const float4*)&Bs[k][gg];
            acc[0][0] = fmaf(a.x, b.x, acc[0][0]);
            acc[0][1] = fmaf(a.x, b.y, acc[0][1]);
            acc[0][2] = fmaf(a.x, b.z, acc[0][2]);
            acc[0][3] = fmaf(a.x, b.w, acc[0][3]);
            acc[1][0] = fmaf(a.y, b.x, acc[1][0]);
            acc[1][1] = fmaf(a.y, b.y, acc[1][1]);
            acc[1][2] = fmaf(a.y, b.z, acc[1][2]);
            acc[1][3] = fmaf(a.y, b.w, acc[1][3]);
            acc[2][0] = fmaf(a.z, b.x, acc[2][0]);
            acc[2][1] = fmaf(a.z, b.y, acc[2][1]);
            acc[2][2] = fmaf(a.z, b.z, acc[2][2]);
            acc[2][3] = fmaf(a.z, b.w, acc[2][3]);
            acc[3][0] = fmaf(a.w, b.x, acc[3][0]);
            acc[3][1] = fmaf(a.w, b.y, acc[3][1]);
            acc[3][2] = fmaf(a.w, b.z, acc[3][2]);
            acc[3][3] = fmaf(a.w, b.w, acc[3][3]);
        }
        __syncthreads();
    }

    float bias[4];
    #pragma unroll
    for (int v = 0; v < 4; ++v)
        bias[v] = b_ih[G0 + gg + v] + b_hh[G0 + gg + v];

    #pragma unroll
    for (int u = 0; u < 4; ++u) {
        int row = R0 + rr + u;
        if (row < VOCAB) {
            float4 o;
            o.x = acc[u][0] + bias[0];
            o.y = acc[u][1] + bias[1];
            o.z = acc[u][2] + bias[2];
            o.w = acc[u][3] + bias[3];
            *(float4*)&proj[(size_t)row * G4 + G0 + gg] = o;
        }
    }
}

// ---------------------------------------------------------------------------
// 4-wave LSTM scan: one block (256 thr) per batch element; wave q computes
// gate group q (32 dot2/lane instead of 128). Gates exchanged via double-
// buffered LDS with ONE builtin s_barrier + manual lgkmcnt(0) per step (NOT
// __syncthreads -- its vmcnt(0) drain would kill the gx prefetch pipeline).
// After the exchange, every wave redundantly computes c,h (replicated state),
// repacks pk locally (dpp+cvt), and proceeds -- no second exchange.
// ---------------------------------------------------------------------------
__global__ __launch_bounds__(256) void lstm_scan(
    const int* __restrict__ x, const float* __restrict__ proj,
    const float* __restrict__ W_hh,
    const float* __restrict__ bn_gamma, const float* __restrict__ bn_beta,
    const float* __restrict__ bn_mean, const float* __restrict__ bn_var,
    const float* __restrict__ fc_w, const float* __restrict__ fc_b,
    float* __restrict__ out)
{
    const int b   = blockIdx.x;
    const int tid = threadIdx.x;
    const int w   = tid >> 6;     // wave id 0..3 == gate group (i,f,g,o)
    const int j   = tid & 63;     // hidden unit

    __shared__ int   toks[TSEQ];            // 8 KB
    __shared__ float gbufA[4][HIDDEN];      // gate exchange, buffer A
    __shared__ float gbufB[4][HIDDEN];      // gate exchange, buffer B
    __shared__ float hb_s[HIDDEN];

    for (int i = tid; i < TSEQ; i += 256) toks[i] = x[b * TSEQ + i];
    __syncthreads();   // once, pre-loop: toks ready for all waves

    // this wave's W_hh row for (gate w, unit j): 32 named f16-pair registers
    const float* Wr = &W_hh[(size_t)(w * HIDDEN + j) * HIDDEN];
#define WR_DECL(n) h2 wr##n;
    REP32(WR_DECL)
#undef WR_DECL
#define WR_LOAD(n) { float2 v = *(const float2*)&Wr[2 * (n)]; \
                     wr##n = h2{(_Float16)v.x, (_Float16)v.y}; }
    REP32(WR_LOAD)
#undef WR_LOAD

    float h = 0.0f, c = 0.0f;
    int pk = 0;   // f16x2 (h_{2m}, h_{2m+1}) in even lane 2m; h=0 -> 0

    const float* projw = proj + (size_t)w * HIDDEN + j;  // this wave's gate col

    // prologue: gx(0), gx(1) in flight; tokens for t+2, t+3 staged
    float gx0 = projw[(size_t)toks[0] * G4];
    float gx1 = projw[(size_t)toks[1] * G4];
    int tk0 = toks[2], tk1 = toks[3];

    // one step: issue gx(t+2), stage tok(t+4), 32 dots, activation, exchange
    // via GB (one barrier), redundant c/h update, local repack.
#define STEP(GB, GXCUR, GXNEW, TKREG, TTOK) { \
        GXNEW = projw[(size_t)(TKREG) * G4];                    /* gx(t+2) */ \
        TKREG = toks[(TTOK) < TSEQ ? (TTOK) : TSEQ - 1];        /* tok(t+4) */ \
        float a0 = GXCUR, a1 = 0.f, a2 = 0.f, a3 = 0.f; \
        REP32(DOT1) \
        float gv = (a0 + a1) + (a2 + a3); \
        float av = (w == 2) ? ftanhf(gv) : fsigmoidf(gv); \
        GB[w][j] = av; \
        asm volatile("s_waitcnt lgkmcnt(0)" ::: "memory"); \
        __builtin_amdgcn_s_barrier(); \
        float gi = GB[0][j], gf = GB[1][j], gg2 = GB[2][j], go = GB[3][j]; \
        c = fmaf(gf, c, gi * gg2); \
        h = go * ftanhf(c); \
        int hp = dpp_xor1(__float_as_int(h)); \
        pk = __builtin_bit_cast(int, \
             __builtin_amdgcn_cvt_pkrtz(h, __int_as_float(hp))); \
    }
#define DOT1(n) { h2 hv = __builtin_bit_cast(h2, rl(pk, 2 * (n))); \
        if      (((n) & 3) == 0) a0 = dot2(wr##n, hv, a0); \
        else if (((n) & 3) == 1) a1 = dot2(wr##n, hv, a1); \
        else if (((n) & 3) == 2) a2 = dot2(wr##n, hv, a2); \
        else                     a3 = dot2(wr##n, hv, a3); }

    for (int t = 0; t < TSEQ; t += 2) {
        float gx0n, gx1n;
        STEP(gbufA, gx0, gx0n, tk0, t + 4)    // step t   (buffer A)
        STEP(gbufB, gx1, gx1n, tk1, t + 5)    // step t+1 (buffer B)
        gx0 = gx0n; gx1 = gx1n;
    }
#undef DOT1
#undef STEP

    // epilogue: h is replicated in every wave; wave 0 does BN + FC
    if (w == 0) {
        float hb = (h - bn_mean[j]) * rsqrtf(bn_var[j] + 1e-5f) * bn_gamma[j]
                   + bn_beta[j];
        hb_s[j] = hb;
        // intra-wave LDS: compiler inserts the lgkmcnt before the reads
        if (j < NUM_OUT) {
            float s0 = fc_b[j], s1 = 0.f, s2 = 0.f, s3 = 0.f;
            #pragma unroll
            for (int k = 0; k < HIDDEN; k += 4) {
                s0 = fmaf(hb_s[k + 0], fc_w[j * HIDDEN + k + 0], s0);
                s1 = fmaf(hb_s[k + 1], fc_w[j * HIDDEN + k + 1], s1);
                s2 = fmaf(hb_s[k + 2], fc_w[j * HIDDEN + k + 2], s2);
                s3 = fmaf(hb_s[k + 3], fc_w[j * HIDDEN + k + 3], s3);
            }
            out[b * NUM_OUT + j] = (s0 + s1) + (s2 + s3);
        }
    }
}

// ---------------------------------------------------------------------------
extern "C" void kernel_launch(void* const* d_in, const int* in_sizes, int n_in,
                              void* d_out, int out_size, void* d_ws, size_t ws_size,
                              hipStream_t stream) {
    const int*   x        = (const int*)d_in[0];
    // d_in[1] = seq_lengths: unused by the reference computation
    const float* emb      = (const float*)d_in[2];
    const float* W_ih     = (const float*)d_in[3];
    const float* W_hh     = (const float*)d_in[4];
    const float* b_ih     = (const float*)d_in[5];
    const float* b_hh     = (const float*)d_in[6];
    const float* bn_gamma = (const float*)d_in[7];
    const float* bn_beta  = (const float*)d_in[8];
    const float* bn_mean  = (const float*)d_in[9];
    const float* bn_var   = (const float*)d_in[10];
    const float* fc_w     = (const float*)d_in[11];
    const float* fc_b     = (const float*)d_in[12];

    float* proj = (float*)d_ws;  // VOCAB * 256 * 4 B = 51.2 MB

    dim3 pgrid((VOCAB + 63) / 64, G4 / 64);
    proj_kernel<<<pgrid, 256, 0, stream>>>(emb, W_ih, b_ih, b_hh, proj);

    lstm_scan<<<BATCH, 256, 0, stream>>>(x, proj, W_hh,
                                         bn_gamma, bn_beta, bn_mean, bn_var,
                                         fc_w, fc_b, (float*)d_out);
}

// Round 9
// 666.090 us; speedup vs baseline: 1.7137x; 1.4353x over previous
//
#include <hip/hip_runtime.h>
#include <math.h>

#define VOCAB   50000
#define EMBED   256
#define HIDDEN  64
#define G4      256     // 4*HIDDEN
#define BATCH   64
#define TSEQ    2048
#define NUM_OUT 16

typedef _Float16 h2 __attribute__((ext_vector_type(2)));

__device__ __forceinline__ float fexp2f(float x) { return __builtin_amdgcn_exp2f(x); }
__device__ __forceinline__ float frcpf(float x)  { return __builtin_amdgcn_rcpf(x); }

// f16x2 dot with fp32 accumulate — v_dot2_f32_f16
__device__ __forceinline__ float dot2(h2 a, h2 b, float c) {
#if __has_builtin(__builtin_amdgcn_fdot2)
    return __builtin_amdgcn_fdot2(a, b, c, false);
#else
    float r;
    asm("v_dot2_f32_f16 %0, %1, %2, %3"
        : "=v"(r)
        : "v"(__builtin_bit_cast(int, a)), "v"(__builtin_bit_cast(int, b)), "v"(c));
    return r;
#endif
}

// quad_perm DPP: pure-VALU intra-quad exchange
template <int CTRL>
__device__ __forceinline__ float dppf(float v) {
    return __int_as_float(__builtin_amdgcn_update_dpp(
        0, __float_as_int(v), CTRL, 0xF, 0xF, true));
}

#define REP32(M) M(0) M(1) M(2) M(3) M(4) M(5) M(6) M(7) \
                 M(8) M(9) M(10) M(11) M(12) M(13) M(14) M(15) \
                 M(16) M(17) M(18) M(19) M(20) M(21) M(22) M(23) \
                 M(24) M(25) M(26) M(27) M(28) M(29) M(30) M(31)

// ---------------------------------------------------------------------------
// proj[v][g] = dot(emb[v], W_ih[g]) + b_ih[g] + b_hh[g]   (gate-major, R8)
// ---------------------------------------------------------------------------
__global__ __launch_bounds__(256) void proj_kernel(
    const float* __restrict__ emb, const float* __restrict__ W_ih,
    const float* __restrict__ b_ih, const float* __restrict__ b_hh,
    float* __restrict__ proj)
{
    __shared__ __align__(16) float As[64][68];
    __shared__ __align__(16) float Bs[64][68];

    const int tid = threadIdx.x;
    const int R0 = blockIdx.x * 64;
    const int G0 = blockIdx.y * 64;

    const int rr = (tid & 15) * 4;
    const int gg = (tid >> 4) * 4;

    float acc[4][4] = {};

    for (int kc = 0; kc < 4; ++kc) {
        #pragma unroll
        for (int it = 0; it < 4; ++it) {
            int flat = (it * 256 + tid) * 4;
            int r = flat >> 6;
            int k = flat & 63;
            int row = R0 + r;
            float4 v = make_float4(0.f, 0.f, 0.f, 0.f);
            if (row < VOCAB)
                v = *(const float4*)&emb[(size_t)row * EMBED + kc * 64 + k];
            As[k + 0][r] = v.x; As[k + 1][r] = v.y;
            As[k + 2][r] = v.z; As[k + 3][r] = v.w;
            float4 wv = *(const float4*)&W_ih[(size_t)(G0 + r) * EMBED + kc * 64 + k];
            Bs[k + 0][r] = wv.x; Bs[k + 1][r] = wv.y;
            Bs[k + 2][r] = wv.z; Bs[k + 3][r] = wv.w;
        }
        __syncthreads();

        #pragma unroll 8
        for (int k = 0; k < 64; ++k) {
            float4 a = *(const float4*)&As[k][rr];
            float4 b = *(const float4*)&Bs[k][gg];
            acc[0][0] = fmaf(a.x, b.x, acc[0][0]);
            acc[0][1] = fmaf(a.x, b.y, acc[0][1]);
            acc[0][2] = fmaf(a.x, b.z, acc[0][2]);
            acc[0][3] = fmaf(a.x, b.w, acc[0][3]);
            acc[1][0] = fmaf(a.y, b.x, acc[1][0]);
            acc[1][1] = fmaf(a.y, b.y, acc[1][1]);
            acc[1][2] = fmaf(a.y, b.z, acc[1][2]);
            acc[1][3] = fmaf(a.y, b.w, acc[1][3]);
            acc[2][0] = fmaf(a.z, b.x, acc[2][0]);
            acc[2][1] = fmaf(a.z, b.y, acc[2][1]);
            acc[2][2] = fmaf(a.z, b.z, acc[2][2]);
            acc[2][3] = fmaf(a.z, b.w, acc[2][3]);
            acc[3][0] = fmaf(a.w, b.x, acc[3][0]);
            acc[3][1] = fmaf(a.w, b.y, acc[3][1]);
            acc[3][2] = fmaf(a.w, b.z, acc[3][2]);
            acc[3][3] = fmaf(a.w, b.w, acc[3][3]);
        }
        __syncthreads();
    }

    float bias[4];
    #pragma unroll
    for (int v = 0; v < 4; ++v)
        bias[v] = b_ih[G0 + gg + v] + b_hh[G0 + gg + v];

    #pragma unroll
    for (int u = 0; u < 4; ++u) {
        int row = R0 + rr + u;
        if (row < VOCAB) {
            float4 o;
            o.x = acc[u][0] + bias[0];
            o.y = acc[u][1] + bias[1];
            o.z = acc[u][2] + bias[2];
            o.w = acc[u][3] + bias[3];
            *(float4*)&proj[(size_t)row * G4 + G0 + gg] = o;
        }
    }
}

// ---------------------------------------------------------------------------
// 4-wave LSTM scan, quad-local gates: lane l = gate q (l&3) of unit 16w+(l>>2).
// Gate combine = 3 quad_perm DPPs + cndmask (VALU, no LDS). c,h updated
// redundantly in all lanes of the quad. Only h crosses waves: f16 ds_write_b16
// (q==0 lanes), ONE s_barrier, then 8x ds_read_b128 broadcast (all lanes same
// address, conflict-free) replaces 32 readlanes. Double-buffered h.
// ---------------------------------------------------------------------------
__global__ __launch_bounds__(256) void lstm_scan(
    const int* __restrict__ x, const float* __restrict__ proj,
    const float* __restrict__ W_hh,
    const float* __restrict__ bn_gamma, const float* __restrict__ bn_beta,
    const float* __restrict__ bn_mean, const float* __restrict__ bn_var,
    const float* __restrict__ fc_w, const float* __restrict__ fc_b,
    float* __restrict__ out)
{
    const int b   = blockIdx.x;
    const int tid = threadIdx.x;
    const int w   = tid >> 6;        // wave 0..3: units 16w .. 16w+15
    const int l   = tid & 63;
    const int q   = l & 3;           // gate index (i,f,g,o)
    const int unit = w * 16 + (l >> 2);

    __shared__ int   toks[TSEQ];                 // 8 KB
    __shared__ __align__(16) short hbuf[2][HIDDEN];  // f16 h, double-buffered
    __shared__ float hfin[HIDDEN];
    __shared__ float hb_s[HIDDEN];

    for (int i = tid; i < TSEQ; i += 256) toks[i] = x[b * TSEQ + i];
    if (tid < 2 * HIDDEN) ((short*)hbuf)[tid] = 0;   // h(-1) = 0 (both bufs)

    // this lane's W_hh row (gate q, unit) as 32 named f16-pair registers
    const float* Wr = &W_hh[(size_t)(q * HIDDEN + unit) * HIDDEN];
#define WR_DECL(n) h2 wr##n;
    REP32(WR_DECL)
#undef WR_DECL
#define WR_LOAD(n) { float2 v = *(const float2*)&Wr[2 * (n)]; \
                     wr##n = h2{(_Float16)v.x, (_Float16)v.y}; }
    REP32(WR_LOAD)
#undef WR_LOAD

    // branchless activation constants: sig(x)=1-1/(2^(kx)+1), tanh=1-2/(2^(2kx)+1)
    const float s_k = (q == 2) ? 2.8853900817779268f : 1.4426950408889634f;
    const float s_m = (q == 2) ? 2.0f : 1.0f;
    const bool qodd = (q & 1) != 0;
    const bool qhi  = (q & 2) != 0;

    float c = 0.0f, hmy = 0.0f;
    const float* projw = proj + q * HIDDEN + unit;   // gate-major column

    __syncthreads();

    // 2-step-deep gx prefetch
    float gx0 = projw[(size_t)toks[0] * G4];
    float gx1 = projw[(size_t)toks[1] * G4];
    int tk0 = toks[2], tk1 = toks[3];

#define DOTG(R, W0, W1, W2, W3) \
    a0 = dot2(W0, __builtin_bit_cast(h2, R.x), a0); \
    a1 = dot2(W1, __builtin_bit_cast(h2, R.y), a1); \
    a2 = dot2(W2, __builtin_bit_cast(h2, R.z), a2); \
    a3 = dot2(W3, __builtin_bit_cast(h2, R.w), a3);

#define STEP(RP, WP, GXCUR, GXNEW, TKREG, TTOK) { \
    GXNEW = projw[(size_t)(TKREG) * G4];                 /* gx(t+2) */ \
    TKREG = toks[(TTOK) < TSEQ ? (TTOK) : TSEQ - 1];     /* tok(t+4) */ \
    const int4* hp = (const int4*)hbuf[RP];              /* broadcast reads */ \
    int4 r0 = hp[0], r1 = hp[1], r2 = hp[2], r3 = hp[3]; \
    int4 r4 = hp[4], r5 = hp[5], r6 = hp[6], r7 = hp[7]; \
    float a0 = GXCUR, a1 = 0.f, a2 = 0.f, a3 = 0.f; \
    DOTG(r0, wr0,  wr1,  wr2,  wr3)  DOTG(r1, wr4,  wr5,  wr6,  wr7) \
    DOTG(r2, wr8,  wr9,  wr10, wr11) DOTG(r3, wr12, wr13, wr14, wr15) \
    DOTG(r4, wr16, wr17, wr18, wr19) DOTG(r5, wr20, wr21, wr22, wr23) \
    DOTG(r6, wr24, wr25, wr26, wr27) DOTG(r7, wr28, wr29, wr30, wr31) \
    float gv = (a0 + a1) + (a2 + a3); \
    float tt = fexp2f(s_k * gv); \
    float rr = 1.0f - s_m * frcpf(tt + 1.0f);            /* act(own gate) */ \
    float b1 = dppf<0xB1>(rr);                           /* quad xor1 */ \
    float b2 = dppf<0x4E>(rr);                           /* quad xor2 */ \
    float b3 = dppf<0x1B>(rr);                           /* quad xor3 */ \
    float A  = qodd ? b1 : rr,  B  = qodd ? b3 : b2; \
    float A2 = qodd ? rr : b1,  B2 = qodd ? b2 : b3; \
    float i_ = qhi ? B  : A,    g_ = qhi ? A  : B; \
    float f_ = qhi ? B2 : A2,   o_ = qhi ? A2 : B2; \
    c = fmaf(f_, c, i_ * g_); \
    float e2 = fexp2f(2.8853900817779268f * c); \
    float th = 1.0f - 2.0f * frcpf(e2 + 1.0f);           /* tanh(c) */ \
    hmy = o_ * th; \
    if (q == 0) hbuf[WP][unit] = __builtin_bit_cast(short, (_Float16)hmy); \
    asm volatile("s_waitcnt lgkmcnt(0)" ::: "memory"); \
    __builtin_amdgcn_s_barrier(); \
}

    for (int t = 0; t < TSEQ; t += 2) {
        float gx0n, gx1n;
        STEP(0, 1, gx0, gx0n, tk0, t + 4)    // even step: read buf0, write buf1
        STEP(1, 0, gx1, gx1n, tk1, t + 5)    // odd  step: read buf1, write buf0
        gx0 = gx0n; gx1 = gx1n;
    }
#undef STEP
#undef DOTG

    // epilogue: final h (f32, replicated per quad) -> BN -> FC
    if (q == 0) hfin[unit] = hmy;
    __syncthreads();
    if (tid < HIDDEN) {
        float hb = (hfin[tid] - bn_mean[tid]) * rsqrtf(bn_var[tid] + 1e-5f)
                   * bn_gamma[tid] + bn_beta[tid];
        hb_s[tid] = hb;
    }
    __syncthreads();
    if (tid < NUM_OUT) {
        float s0 = fc_b[tid], s1 = 0.f, s2 = 0.f, s3 = 0.f;
        #pragma unroll
        for (int k = 0; k < HIDDEN; k += 4) {
            s0 = fmaf(hb_s[k + 0], fc_w[tid * HIDDEN + k + 0], s0);
            s1 = fmaf(hb_s[k + 1], fc_w[tid * HIDDEN + k + 1], s1);
            s2 = fmaf(hb_s[k + 2], fc_w[tid * HIDDEN + k + 2], s2);
            s3 = fmaf(hb_s[k + 3], fc_w[tid * HIDDEN + k + 3], s3);
        }
        out[b * NUM_OUT + tid] = (s0 + s1) + (s2 + s3);
    }
}

// ---------------------------------------------------------------------------
extern "C" void kernel_launch(void* const* d_in, const int* in_sizes, int n_in,
                              void* d_out, int out_size, void* d_ws, size_t ws_size,
                              hipStream_t stream) {
    const int*   x        = (const int*)d_in[0];
    // d_in[1] = seq_lengths: unused by the reference computation
    const float* emb      = (const float*)d_in[2];
    const float* W_ih     = (const float*)d_in[3];
    const float* W_hh     = (const float*)d_in[4];
    const float* b_ih     = (const float*)d_in[5];
    const float* b_hh     = (const float*)d_in[6];
    const float* bn_gamma = (const float*)d_in[7];
    const float* bn_beta  = (const float*)d_in[8];
    const float* bn_mean  = (const float*)d_in[9];
    const float* bn_var   = (const float*)d_in[10];
    const float* fc_w     = (const float*)d_in[11];
    const float* fc_b     = (const float*)d_in[12];

    float* proj = (float*)d_ws;  // VOCAB * 256 * 4 B = 51.2 MB

    dim3 pgrid((VOCAB + 63) / 64, G4 / 64);
    proj_kernel<<<pgrid, 256, 0, stream>>>(emb, W_ih, b_ih, b_hh, proj);

    lstm_scan<<<BATCH, 256, 0, stream>>>(x, proj, W_hh,
                                         bn_gamma, bn_beta, bn_mean, bn_var,
                                         fc_w, fc_b, (float*)d_out);
}

// Round 10
// 652.255 us; speedup vs baseline: 1.7501x; 1.0212x over previous
//
#include <hip/hip_runtime.h>
#include <math.h>

#define VOCAB   50000
#define EMBED   256
#define HIDDEN  64
#define G4      256     // 4*HIDDEN
#define BATCH   64
#define TSEQ    2048
#define NUM_OUT 16

typedef _Float16 h2 __attribute__((ext_vector_type(2)));

__device__ __forceinline__ float fexp2f(float x) { return __builtin_amdgcn_exp2f(x); }
__device__ __forceinline__ float frcpf(float x)  { return __builtin_amdgcn_rcpf(x); }

// f16x2 dot with fp32 accumulate — v_dot2_f32_f16
__device__ __forceinline__ float dot2(h2 a, h2 b, float c) {
#if __has_builtin(__builtin_amdgcn_fdot2)
    return __builtin_amdgcn_fdot2(a, b, c, false);
#else
    float r;
    asm("v_dot2_f32_f16 %0, %1, %2, %3"
        : "=v"(r)
        : "v"(__builtin_bit_cast(int, a)), "v"(__builtin_bit_cast(int, b)), "v"(c));
    return r;
#endif
}

// quad_perm DPP: pure-VALU intra-quad exchange
template <int CTRL>
__device__ __forceinline__ float dppf(float v) {
    return __int_as_float(__builtin_amdgcn_update_dpp(
        0, __float_as_int(v), CTRL, 0xF, 0xF, true));
}

#define REP32(M) M(0) M(1) M(2) M(3) M(4) M(5) M(6) M(7) \
                 M(8) M(9) M(10) M(11) M(12) M(13) M(14) M(15) \
                 M(16) M(17) M(18) M(19) M(20) M(21) M(22) M(23) \
                 M(24) M(25) M(26) M(27) M(28) M(29) M(30) M(31)

// ---------------------------------------------------------------------------
// proj[v][g] = dot(emb[v], W_ih[g]) + b_ih[g] + b_hh[g]   (gate-major)
// ---------------------------------------------------------------------------
__global__ __launch_bounds__(256) void proj_kernel(
    const float* __restrict__ emb, const float* __restrict__ W_ih,
    const float* __restrict__ b_ih, const float* __restrict__ b_hh,
    float* __restrict__ proj)
{
    __shared__ __align__(16) float As[64][68];
    __shared__ __align__(16) float Bs[64][68];

    const int tid = threadIdx.x;
    const int R0 = blockIdx.x * 64;
    const int G0 = blockIdx.y * 64;

    const int rr = (tid & 15) * 4;
    const int gg = (tid >> 4) * 4;

    float acc[4][4] = {};

    for (int kc = 0; kc < 4; ++kc) {
        #pragma unroll
        for (int it = 0; it < 4; ++it) {
            int flat = (it * 256 + tid) * 4;
            int r = flat >> 6;
            int k = flat & 63;
            int row = R0 + r;
            float4 v = make_float4(0.f, 0.f, 0.f, 0.f);
            if (row < VOCAB)
                v = *(const float4*)&emb[(size_t)row * EMBED + kc * 64 + k];
            As[k + 0][r] = v.x; As[k + 1][r] = v.y;
            As[k + 2][r] = v.z; As[k + 3][r] = v.w;
            float4 wv = *(const float4*)&W_ih[(size_t)(G0 + r) * EMBED + kc * 64 + k];
            Bs[k + 0][r] = wv.x; Bs[k + 1][r] = wv.y;
            Bs[k + 2][r] = wv.z; Bs[k + 3][r] = wv.w;
        }
        __syncthreads();

        #pragma unroll 8
        for (int k = 0; k < 64; ++k) {
            float4 a = *(const float4*)&As[k][rr];
            float4 b = *(const float4*)&Bs[k][gg];
            acc[0][0] = fmaf(a.x, b.x, acc[0][0]);
            acc[0][1] = fmaf(a.x, b.y, acc[0][1]);
            acc[0][2] = fmaf(a.x, b.z, acc[0][2]);
            acc[0][3] = fmaf(a.x, b.w, acc[0][3]);
            acc[1][0] = fmaf(a.y, b.x, acc[1][0]);
            acc[1][1] = fmaf(a.y, b.y, acc[1][1]);
            acc[1][2] = fmaf(a.y, b.z, acc[1][2]);
            acc[1][3] = fmaf(a.y, b.w, acc[1][3]);
            acc[2][0] = fmaf(a.z, b.x, acc[2][0]);
            acc[2][1] = fmaf(a.z, b.y, acc[2][1]);
            acc[2][2] = fmaf(a.z, b.z, acc[2][2]);
            acc[2][3] = fmaf(a.z, b.w, acc[2][3]);
            acc[3][0] = fmaf(a.w, b.x, acc[3][0]);
            acc[3][1] = fmaf(a.w, b.y, acc[3][1]);
            acc[3][2] = fmaf(a.w, b.z, acc[3][2]);
            acc[3][3] = fmaf(a.w, b.w, acc[3][3]);
        }
        __syncthreads();
    }

    float bias[4];
    #pragma unroll
    for (int v = 0; v < 4; ++v)
        bias[v] = b_ih[G0 + gg + v] + b_hh[G0 + gg + v];

    #pragma unroll
    for (int u = 0; u < 4; ++u) {
        int row = R0 + rr + u;
        if (row < VOCAB) {
            float4 o;
            o.x = acc[u][0] + bias[0];
            o.y = acc[u][1] + bias[1];
            o.z = acc[u][2] + bias[2];
            o.w = acc[u][3] + bias[3];
            *(float4*)&proj[(size_t)row * G4 + G0 + gg] = o;
        }
    }
}

// ---------------------------------------------------------------------------
// 4-wave LSTM scan, quad-local gates (R9 structure) with chain-latency cuts:
//  - broadcast h reads issue FIRST (chain head)
//  - gx prefetch depth 4, fixed register roles (4-step unrolled loop)
//  - gx joins the dot reduce at the END (vmcnt wait hides under dots)
//  - toks read 8 steps ahead, issued at step top (drains under dots+act)
// ---------------------------------------------------------------------------
__global__ __launch_bounds__(256) void lstm_scan(
    const int* __restrict__ x, const float* __restrict__ proj,
    const float* __restrict__ W_hh,
    const float* __restrict__ bn_gamma, const float* __restrict__ bn_beta,
    const float* __restrict__ bn_mean, const float* __restrict__ bn_var,
    const float* __restrict__ fc_w, const float* __restrict__ fc_b,
    float* __restrict__ out)
{
    const int b   = blockIdx.x;
    const int tid = threadIdx.x;
    const int w   = tid >> 6;        // wave 0..3: units 16w .. 16w+15
    const int l   = tid & 63;
    const int q   = l & 3;           // gate index (i,f,g,o)
    const int unit = w * 16 + (l >> 2);

    __shared__ int   toks[TSEQ];                     // 8 KB
    __shared__ __align__(16) short hbuf[2][HIDDEN];  // f16 h, double-buffered
    __shared__ float hfin[HIDDEN];
    __shared__ float hb_s[HIDDEN];

    for (int i = tid; i < TSEQ; i += 256) toks[i] = x[b * TSEQ + i];
    if (tid < 2 * HIDDEN) ((short*)hbuf)[tid] = 0;   // h(-1) = 0 (both bufs)

    // this lane's W_hh row (gate q, unit) as 32 named f16-pair registers
    const float* Wr = &W_hh[(size_t)(q * HIDDEN + unit) * HIDDEN];
#define WR_DECL(n) h2 wr##n;
    REP32(WR_DECL)
#undef WR_DECL
#define WR_LOAD(n) { float2 v = *(const float2*)&Wr[2 * (n)]; \
                     wr##n = h2{(_Float16)v.x, (_Float16)v.y}; }
    REP32(WR_LOAD)
#undef WR_LOAD

    // branchless activation: sig(x)=1-1/(2^(kx)+1), tanh=1-2/(2^(2kx)+1)
    const float s_k = (q == 2) ? 2.8853900817779268f : 1.4426950408889634f;
    const float s_m = (q == 2) ? 2.0f : 1.0f;
    const bool qodd = (q & 1) != 0;
    const bool qhi  = (q & 2) != 0;

    float c = 0.0f, hmy = 0.0f;
    const float* projw = proj + q * HIDDEN + unit;   // gate-major column

    __syncthreads();

    // prologue: gx(0..3) in flight (depth 4); tokens for t=4..7 staged
    float gx0 = projw[(size_t)toks[0] * G4];
    float gx1 = projw[(size_t)toks[1] * G4];
    float gx2 = projw[(size_t)toks[2] * G4];
    float gx3 = projw[(size_t)toks[3] * G4];
    int tk0 = toks[4], tk1 = toks[5], tk2 = toks[6], tk3 = toks[7];

#define DOTG(R, W0, W1, W2, W3) \
    a0 = dot2(W0, __builtin_bit_cast(h2, R.x), a0); \
    a1 = dot2(W1, __builtin_bit_cast(h2, R.y), a1); \
    a2 = dot2(W2, __builtin_bit_cast(h2, R.z), a2); \
    a3 = dot2(W3, __builtin_bit_cast(h2, R.w), a3);

    // STEP: RP/WP = read/write h buffer; GX = this step's gx (refilled for
    // t+4); TK = token t+4 (refilled with token t+8).
#define STEP(RP, WP, GX, TK, TTOK) { \
    /* chain head: broadcast h reads (8 x b128, all lanes same address) */ \
    const int4* hp = (const int4*)hbuf[RP]; \
    int4 r0 = hp[0], r1 = hp[1], r2 = hp[2], r3 = hp[3]; \
    int4 r4 = hp[4], r5 = hp[5], r6 = hp[6], r7 = hp[7]; \
    /* off-chain refills: toks 8 ahead, gx 4 ahead (drain under dots) */ \
    int tnew = toks[(TTOK) + 8 < TSEQ ? (TTOK) + 8 : TSEQ - 1]; \
    float gnew = projw[(size_t)(TK) * G4]; \
    float a0 = 0.f, a1 = 0.f, a2 = 0.f, a3 = 0.f; \
    DOTG(r0, wr0,  wr1,  wr2,  wr3)  DOTG(r1, wr4,  wr5,  wr6,  wr7) \
    DOTG(r2, wr8,  wr9,  wr10, wr11) DOTG(r3, wr12, wr13, wr14, wr15) \
    DOTG(r4, wr16, wr17, wr18, wr19) DOTG(r5, wr20, wr21, wr22, wr23) \
    DOTG(r6, wr24, wr25, wr26, wr27) DOTG(r7, wr28, wr29, wr30, wr31) \
    float gv = ((a0 + a1) + (a2 + a3)) + GX;   /* vmcnt wait lands HERE */ \
    GX = gnew; TK = tnew; \
    float tt = fexp2f(s_k * gv); \
    float rr = 1.0f - s_m * frcpf(tt + 1.0f);            /* act(own gate) */ \
    float b1 = dppf<0xB1>(rr);                           /* quad xor1 */ \
    float b2 = dppf<0x4E>(rr);                           /* quad xor2 */ \
    float b3 = dppf<0x1B>(rr);                           /* quad xor3 */ \
    float A  = qodd ? b1 : rr,  B  = qodd ? b3 : b2; \
    float A2 = qodd ? rr : b1,  B2 = qodd ? b2 : b3; \
    float i_ = qhi ? B  : A,    g_ = qhi ? A  : B; \
    float f_ = qhi ? B2 : A2,   o_ = qhi ? A2 : B2; \
    c = fmaf(f_, c, i_ * g_); \
    float e2 = fexp2f(2.8853900817779268f * c); \
    float th = 1.0f - 2.0f * frcpf(e2 + 1.0f);           /* tanh(c) */ \
    hmy = o_ * th; \
    if (q == 0) hbuf[WP][unit] = __builtin_bit_cast(short, (_Float16)hmy); \
    asm volatile("s_waitcnt lgkmcnt(0)" ::: "memory"); \
    __builtin_amdgcn_s_barrier(); \
}

    for (int t = 0; t < TSEQ; t += 4) {
        STEP(0, 1, gx0, tk0, t)
        STEP(1, 0, gx1, tk1, t + 1)
        STEP(0, 1, gx2, tk2, t + 2)
        STEP(1, 0, gx3, tk3, t + 3)
    }
#undef STEP
#undef DOTG

    // epilogue: final h (replicated per quad) -> BN -> FC
    if (q == 0) hfin[unit] = hmy;
    __syncthreads();
    if (tid < HIDDEN) {
        float hb = (hfin[tid] - bn_mean[tid]) * rsqrtf(bn_var[tid] + 1e-5f)
                   * bn_gamma[tid] + bn_beta[tid];
        hb_s[tid] = hb;
    }
    __syncthreads();
    if (tid < NUM_OUT) {
        float s0 = fc_b[tid], s1 = 0.f, s2 = 0.f, s3 = 0.f;
        #pragma unroll
        for (int k = 0; k < HIDDEN; k += 4) {
            s0 = fmaf(hb_s[k + 0], fc_w[tid * HIDDEN + k + 0], s0);
            s1 = fmaf(hb_s[k + 1], fc_w[tid * HIDDEN + k + 1], s1);
            s2 = fmaf(hb_s[k + 2], fc_w[tid * HIDDEN + k + 2], s2);
            s3 = fmaf(hb_s[k + 3], fc_w[tid * HIDDEN + k + 3], s3);
        }
        out[b * NUM_OUT + tid] = (s0 + s1) + (s2 + s3);
    }
}

// ---------------------------------------------------------------------------
extern "C" void kernel_launch(void* const* d_in, const int* in_sizes, int n_in,
                              void* d_out, int out_size, void* d_ws, size_t ws_size,
                              hipStream_t stream) {
    const int*   x        = (const int*)d_in[0];
    // d_in[1] = seq_lengths: unused by the reference computation
    const float* emb      = (const float*)d_in[2];
    const float* W_ih     = (const float*)d_in[3];
    const float* W_hh     = (const float*)d_in[4];
    const float* b_ih     = (const float*)d_in[5];
    const float* b_hh     = (const float*)d_in[6];
    const float* bn_gamma = (const float*)d_in[7];
    const float* bn_beta  = (const float*)d_in[8];
    const float* bn_mean  = (const float*)d_in[9];
    const float* bn_var   = (const float*)d_in[10];
    const float* fc_w     = (const float*)d_in[11];
    const float* fc_b     = (const float*)d_in[12];

    float* proj = (float*)d_ws;  // VOCAB * 256 * 4 B = 51.2 MB

    dim3 pgrid((VOCAB + 63) / 64, G4 / 64);
    proj_kernel<<<pgrid, 256, 0, stream>>>(emb, W_ih, b_ih, b_hh, proj);

    lstm_scan<<<BATCH, 256, 0, stream>>>(x, proj, W_hh,
                                         bn_gamma, bn_beta, bn_mean, bn_var,
                                         fc_w, fc_b, (float*)d_out);
}